// Round 21
// baseline (461.506 us; speedup 1.0000x reference)
//
#include <hip/hip_runtime.h>
#include <math.h>

#define MID 512
#define NB  65536
#define G   4096
#define NBLK 516            // blocks per net, 8 points each
#define PTS  4128           // grid points per net; point p -> x = (p-1)/G

struct NetP { const float *w1,*b1,*w2,*b2,*w3,*b3; };
struct AllP { NetP n[3]; float* table; };

// ---------------------------------------------------------------------------
// Kernel 0: transpose W2 (512x512) -> W2T[k][n] per net.
// ---------------------------------------------------------------------------
__global__ __launch_bounds__(256)
void k_prep(AllP P, float* __restrict__ w2t)
{
    __shared__ float t[32][33];
    const int net = blockIdx.z;
    const float* src = (net == 0) ? P.n[0].w2 : (net == 1) ? P.n[1].w2 : P.n[2].w2;
    float* dst = w2t + (size_t)net * MID * MID;
    const int bx = blockIdx.x * 32, by = blockIdx.y * 32;
    const int tx = threadIdx.x & 31, ty = threadIdx.x >> 5;   // ty 0..7
    #pragma unroll
    for (int j = 0; j < 4; ++j)
        t[ty + 8 * j][tx] = src[(size_t)(by + ty + 8 * j) * MID + bx + tx];
    __syncthreads();
    #pragma unroll
    for (int j = 0; j < 4; ++j)
        dst[(size_t)(bx + ty + 8 * j) * MID + by + tx] = t[tx][ty + 8 * j];
}

// ---------------------------------------------------------------------------
// Kernel 1: fused SIREN, 256 threads x 8 points/block, 1548 blocks (6.05/CU,
// ~24 waves/CU). R9-R20: 13 variants at 3 blocks/CU all pinned 173-200us with
// Occupancy 16-21% — every per-pipe theory refuted; the untested lever is
// TLP. Halving points/block doubles blocks & waves/CU at identical total FMA
// (LDS 16KB -> 9 blocks/CU possible, grid gives 6).
// Tile: P=8 pts x C=2 cols/thread (16 acc floats, VGPR~70). Barrier-free
// R18-style k-loop: 1 global b64 (W, L2) + 2 broadcast LDS b128 (h) / k.
// Layer 3: h2 [8][512] in same buffer; f2 stores XOR key 2i == f4 reads key
// (qq^m) (2qq^2m = 2(qq^m)); both sides conflict-free.
// ---------------------------------------------------------------------------
__global__ __attribute__((amdgpu_waves_per_eu(2, 8))) __launch_bounds__(256)
void k_siren(AllP P, const float* __restrict__ w2t)
{
    __shared__ float sbuf[MID * 8];     // 16 KB: h1 [k][m] during loop; h2 after

    const int tid = threadIdx.x;
    const int net = blockIdx.y;
    const int m0  = blockIdx.x * 8;
    NetP np;
    if (net == 0)      np = P.n[0];
    else if (net == 1) np = P.n[1];
    else               np = P.n[2];
    const float* wslab = w2t + (size_t)net * MID * MID;

    const int c  = tid & 63;
    const int w  = tid >> 6;          // wave 0..3 -> col quarter
    const int cw = w * 128 + c * 2;   // first of this thread's 2 cols

    // ---- fill h1[k][m] = sin(sin(4*(x_m*w1[k]+b1[k]))), 16 entries/thread
    {
        const float invG = 1.0f / (float)G;
        #pragma unroll 4
        for (int j = 0; j < 16; ++j) {
            const int idx = tid + j * 256;        // = k*8 + m
            const int k = idx >> 3, m = idx & 7;
            const float xv = ((float)(m0 + m) - 1.0f) * invG;
            const float z = 4.f * fmaf(xv, np.w1[k], np.b1[k]);
            sbuf[idx] = sinf(sinf(z));
        }
    }
    __syncthreads();

#define ACC_DECL(i) float2 a##i = make_float2(0.f, 0.f);
    ACC_DECL(0) ACC_DECL(1) ACC_DECL(2) ACC_DECL(3)
    ACC_DECL(4) ACC_DECL(5) ACC_DECL(6) ACC_DECL(7)

#define FMA2(i, hv) \
        a##i.x = fmaf(hv, wa.x, a##i.x); a##i.y = fmaf(hv, wa.y, a##i.y);

    // ---- K loop: barrier-free. 1 global b64 (W) + 2 broadcast LDS b128 (h).
    {
        const float* wp = wslab + cw;
        #pragma unroll 4
        for (int k = 0; k < MID; ++k) {
            const float2 wa = *reinterpret_cast<const float2*>(wp + (size_t)k * MID);
            const float4 hA = *reinterpret_cast<const float4*>(&sbuf[k * 8 + 0]);
            const float4 hB = *reinterpret_cast<const float4*>(&sbuf[k * 8 + 4]);
            FMA2(0, hA.x) FMA2(1, hA.y) FMA2(2, hA.z) FMA2(3, hA.w)
            FMA2(4, hB.x) FMA2(5, hB.y) FMA2(6, hB.z) FMA2(7, hB.w)
        }
    }
    __syncthreads();   // h1 no longer needed; sbuf becomes the h2 buffer

    {   // epilogue: h2 = sin(sin(4*(z + b2))) — this thread's 2 cols, 8 pts
        const float2 bv = *reinterpret_cast<const float2*>(np.b2 + cw);
#define SS1(v, b) v = sinf(sinf(4.f * ((v) + (b))));
#define SSROW(i) SS1(a##i.x, bv.x) SS1(a##i.y, bv.y)
        SSROW(0) SSROW(1) SSROW(2) SSROW(3)
        SSROW(4) SSROW(5) SSROW(6) SSROW(7)
    }

    // layer 3 stores: row i gets this thread's f2 at phys f2 (n2 ^ 2i)
    {
        const int n2 = w * 64 + c;   // logical float2 col index 0..255
#define L3ST(i) \
        *reinterpret_cast<float2*>(&sbuf[(i) * 512 + ((n2 ^ (2 * (i))) & 255) * 2]) = a##i;
        L3ST(0) L3ST(1) L3ST(2) L3ST(3)
        L3ST(4) L3ST(5) L3ST(6) L3ST(7)
    }
    __syncthreads();

    {   // m = tid&7 (point), jg = tid>>3 (0..31) -> output col jg
        const int m  = tid & 7;
        const int jg = tid >> 3;
        const float* wr = np.w3 + (size_t)jg * MID;
        float pa = 0.f, pb = 0.f;
        #pragma unroll 8
        for (int qq = 0; qq < 128; ++qq) {
            const float4 h  = *reinterpret_cast<const float4*>(
                &sbuf[m * 512 + ((qq ^ m) & 127) * 4]);
            const float4 wv = *reinterpret_cast<const float4*>(wr + qq * 4);
            pa = fmaf(h.y, wv.y, fmaf(h.x, wv.x, pa));
            pb = fmaf(h.w, wv.w, fmaf(h.z, wv.z, pb));
        }
        P.table[((size_t)net * PTS + (m0 + m)) * 32 + jg] = pa + pb + np.b3[jg];
    }
}

// ---------------------------------------------------------------------------
// Kernel 2: fold mode-3 contraction into the W grid (linearity of CR interp):
// WC[p][r][s] = sum_t Wtable[p][t] * C[r][s][t].  One block per grid point p;
// thread t covers (r = t>>3, s = (t&7)*4..+3); output index = tid*4. ~10us.
// ---------------------------------------------------------------------------
__global__ __launch_bounds__(256)
void k_wc(const float* __restrict__ table, const float* __restrict__ core,
          float* __restrict__ wc)
{
    __shared__ float wrow[32];
    const int p   = blockIdx.x;
    const int tid = threadIdx.x;
    if (tid < 32) wrow[tid] = table[((size_t)2 * PTS + p) * 32 + tid];
    __syncthreads();
    const int r = tid >> 3, s4 = tid & 7;
    const float* cb = core + (size_t)r * 1024 + s4 * 4 * 32;
    float4 acc = make_float4(0.f, 0.f, 0.f, 0.f);
    #pragma unroll
    for (int t4 = 0; t4 < 8; ++t4) {
        const float4 wv = *reinterpret_cast<const float4*>(&wrow[t4 * 4]);
        const float4 c0 = *reinterpret_cast<const float4*>(cb + 0 * 32 + t4 * 4);
        const float4 c1 = *reinterpret_cast<const float4*>(cb + 1 * 32 + t4 * 4);
        const float4 c2 = *reinterpret_cast<const float4*>(cb + 2 * 32 + t4 * 4);
        const float4 c3 = *reinterpret_cast<const float4*>(cb + 3 * 32 + t4 * 4);
        acc.x = fmaf(wv.w, c0.w, fmaf(wv.z, c0.z, fmaf(wv.y, c0.y, fmaf(wv.x, c0.x, acc.x))));
        acc.y = fmaf(wv.w, c1.w, fmaf(wv.z, c1.z, fmaf(wv.y, c1.y, fmaf(wv.x, c1.x, acc.y))));
        acc.z = fmaf(wv.w, c2.w, fmaf(wv.z, c2.z, fmaf(wv.y, c2.y, fmaf(wv.x, c2.x, acc.z))));
        acc.w = fmaf(wv.w, c3.w, fmaf(wv.z, c3.z, fmaf(wv.y, c3.y, fmaf(wv.x, c3.x, acc.w))));
    }
    *reinterpret_cast<float4*>(wc + (size_t)p * 1024 + tid * 4) = acc;
}

// ---------------------------------------------------------------------------
// Kernel 3: per-sample CR interp + folded contraction. 4 threads/sample
// (rh = tid>>6 covers r = rh*8..+7), 64 samples/block, 1024 blocks.
// out = sum_tap cw_tap * sum_r U_r sum_s V_s WC[iw+tap][r][s]
// 4.2 KFMA/sample (was 33K); ZERO LDS in hot loop (VMEM reads of WC rows,
// L2/L3-resident 16.9MB).
// ---------------------------------------------------------------------------
#define F4MA(acc, s, rp, k) { const float4 _v = (rp)[k]; \
    acc.x = fmaf((s), _v.x, acc.x); acc.y = fmaf((s), _v.y, acc.y); \
    acc.z = fmaf((s), _v.z, acc.z); acc.w = fmaf((s), _v.w, acc.w); }

#define GROW8(Pfx, w, rp, off) \
    F4MA(Pfx##0,(w),rp,(off)+0) F4MA(Pfx##1,(w),rp,(off)+1) \
    F4MA(Pfx##2,(w),rp,(off)+2) F4MA(Pfx##3,(w),rp,(off)+3) \
    F4MA(Pfx##4,(w),rp,(off)+4) F4MA(Pfx##5,(w),rp,(off)+5) \
    F4MA(Pfx##6,(w),rp,(off)+6) F4MA(Pfx##7,(w),rp,(off)+7)

// Catmull-Rom setup: x*G is EXACT in fp32 (power-of-two scale).
#define CRSETUP(x_, iv, c0, c1, c2, c3) \
    int iv; float c0, c1, c2, c3; { \
        float xx = (x_) * (float)G; \
        int i = (int)xx; i = i < 0 ? 0 : (i > G - 1 ? G - 1 : i); iv = i; \
        float t = xx - (float)i; \
        float t2 = t * t, t3 = t2 * t; \
        c0 = fmaf(-0.5f, t3, t2) - 0.5f * t; \
        c1 = fmaf(1.5f, t3, fmaf(-2.5f, t2, 1.f)); \
        c2 = fmaf(-1.5f, t3, fmaf(2.f, t2, 0.5f * t)); \
        c3 = 0.5f * (t3 - t2); }

#define DOT4(acc, Vv, Mv) \
    acc = fmaf(Vv.w, Mv.w, fmaf(Vv.z, Mv.z, fmaf(Vv.y, Mv.y, fmaf(Vv.x, Mv.x, acc))));

__global__ __attribute__((amdgpu_waves_per_eu(2, 8))) __launch_bounds__(256)
void k_ic2(const float* __restrict__ table, const float* __restrict__ wc,
           const float* __restrict__ x, float* __restrict__ out)
{
    __shared__ float red[256];

    const int tid = threadIdx.x;
    const int ls  = tid & 63;        // local sample
    const int rh  = tid >> 6;        // 0..3, covers r = rh*8 .. rh*8+7
    const int g   = blockIdx.x * 64 + ls;

    const float xu = x[(size_t)g * 3 + 0];
    const float xv = x[(size_t)g * 3 + 1];
    const float xw = x[(size_t)g * 3 + 2];

#define DECLZ(Pn) float4 Pn = make_float4(0.f,0.f,0.f,0.f);
    DECLZ(V0) DECLZ(V1) DECLZ(V2) DECLZ(V3) DECLZ(V4) DECLZ(V5) DECLZ(V6) DECLZ(V7)

    {   // V net (index 1), full 32
        CRSETUP(xv, iv2, c0, c1, c2, c3)
        const float4* rp = reinterpret_cast<const float4*>(
            table + ((size_t)PTS + iv2) * 32);
        GROW8(V, c0, rp, 0) GROW8(V, c1, rp, 8) GROW8(V, c2, rp, 16) GROW8(V, c3, rp, 24)
    }

    float4 Ua = make_float4(0.f,0.f,0.f,0.f), Ub = make_float4(0.f,0.f,0.f,0.f);
    {   // U net (index 0): 8 values for r = rh*8 .. rh*8+7
        CRSETUP(xu, iu, d0, d1, d2, d3)
        const float4* up4 = reinterpret_cast<const float4*>(
            table + (size_t)iu * 32 + rh * 8);
        F4MA(Ua, d0, up4, 0)  F4MA(Ub, d0, up4, 1)
        F4MA(Ua, d1, up4, 8)  F4MA(Ub, d1, up4, 9)
        F4MA(Ua, d2, up4, 16) F4MA(Ub, d2, up4, 17)
        F4MA(Ua, d3, up4, 24) F4MA(Ub, d3, up4, 25)
    }

    CRSETUP(xw, iw, e0, e1, e2, e3)
    const float4* mp = reinterpret_cast<const float4*>(
        wc + (size_t)iw * 1024 + rh * 256);   // this rh's 8 rows of tap 0

#define RL2(rl, uc) { \
    float rA = 0.f, rB = 0.f, rC = 0.f, rD = 0.f; \
    DOT4(rA, V0, tp[(rl) * 8 + 0]) DOT4(rB, V1, tp[(rl) * 8 + 1]) \
    DOT4(rC, V2, tp[(rl) * 8 + 2]) DOT4(rD, V3, tp[(rl) * 8 + 3]) \
    DOT4(rA, V4, tp[(rl) * 8 + 4]) DOT4(rB, V5, tp[(rl) * 8 + 5]) \
    DOT4(rC, V6, tp[(rl) * 8 + 6]) DOT4(rD, V7, tp[(rl) * 8 + 7]) \
    tsum = fmaf(uc, (rA + rB) + (rC + rD), tsum); }

#define TAPBLK(tap, ew) { \
    const float4* tp = mp + (tap) * 256; \
    float tsum = 0.f; \
    RL2(0, Ua.x) RL2(1, Ua.y) RL2(2, Ua.z) RL2(3, Ua.w) \
    RL2(4, Ub.x) RL2(5, Ub.y) RL2(6, Ub.z) RL2(7, Ub.w) \
    o = fmaf(ew, tsum, o); }

    float o = 0.f;
    TAPBLK(0, e0) TAPBLK(1, e1) TAPBLK(2, e2) TAPBLK(3, e3)

    red[tid] = o;
    __syncthreads();
    if (tid < 64)
        out[blockIdx.x * 64 + tid] =
            red[tid] + red[tid + 64] + red[tid + 128] + red[tid + 192];
}

// ---------------------------------------------------------------------------
extern "C" void kernel_launch(void* const* d_in, const int* in_sizes, int n_in,
                              void* d_out, int out_size, void* d_ws, size_t ws_size,
                              hipStream_t stream)
{
    AllP P;
    for (int net = 0; net < 3; ++net) {
        const int b = 1 + net * 6;
        P.n[net].w1 = (const float*)d_in[b + 0];
        P.n[net].b1 = (const float*)d_in[b + 1];
        P.n[net].w2 = (const float*)d_in[b + 2];
        P.n[net].b2 = (const float*)d_in[b + 3];
        P.n[net].w3 = (const float*)d_in[b + 4];
        P.n[net].b3 = (const float*)d_in[b + 5];
    }
    const float* xin  = (const float*)d_in[0];
    const float* core = (const float*)d_in[19];
    float* wsf   = (float*)d_ws;
    float* table = wsf;                            // 3*4128*32   = 1.58 MB
    float* w2t   = wsf + (size_t)3 * PTS * 32;     // 3*512*512   = 3.00 MB
    float* wc    = w2t + (size_t)3 * MID * MID;    // 4128*1024   = 16.9 MB
    P.table = table;

    k_prep <<<dim3(16, 16, 3), 256, 0, stream>>>(P, w2t);
    k_siren<<<dim3(NBLK, 3), 256, 0, stream>>>(P, w2t);
    k_wc   <<<PTS, 256, 0, stream>>>(table, core, wc);
    k_ic2  <<<NB / 64, 256, 0, stream>>>(table, wc, xin, (float*)d_out);
}

// Round 22
// 279.422 us; speedup vs baseline: 1.6516x; 1.6516x over previous
//
#include <hip/hip_runtime.h>
#include <math.h>

#define MID 512
#define NB  65536
#define G   4096
#define NBLK 516            // k_siren blocks per net, 8 points each
#define PTS  4128           // grid points per net; point p -> x = (p-1)/G

struct NetP { const float *w1,*b1,*w2,*b2,*w3,*b3; };
struct AllP { NetP n[3]; float* table; };

// ---------------------------------------------------------------------------
// Kernel 0: transpose W2 (512x512) -> W2T[k][n] per net.
// ---------------------------------------------------------------------------
__global__ __launch_bounds__(256)
void k_prep(AllP P, float* __restrict__ w2t)
{
    __shared__ float t[32][33];
    const int net = blockIdx.z;
    const float* src = (net == 0) ? P.n[0].w2 : (net == 1) ? P.n[1].w2 : P.n[2].w2;
    float* dst = w2t + (size_t)net * MID * MID;
    const int bx = blockIdx.x * 32, by = blockIdx.y * 32;
    const int tx = threadIdx.x & 31, ty = threadIdx.x >> 5;   // ty 0..7
    #pragma unroll
    for (int j = 0; j < 4; ++j)
        t[ty + 8 * j][tx] = src[(size_t)(by + ty + 8 * j) * MID + bx + tx];
    __syncthreads();
    #pragma unroll
    for (int j = 0; j < 4; ++j)
        dst[(size_t)(bx + ty + 8 * j) * MID + by + tx] = t[tx][ty + 8 * j];
}

// ---------------------------------------------------------------------------
// Kernel 1: fused SIREN, 256 threads x 8 points/block, 1548 blocks (6.05/CU,
// ~24 waves/CU = 2x the TLP of the R9-R20 16-pt shape that was pinned at
// 173-200us / Occupancy 16-21% across 13 per-pipe variants).
// Tile: P=8 pts x C=2 cols/thread (16 acc floats). Barrier-free k-loop:
// 1 global b64 (W, L2) + 2 broadcast LDS b128 (h) per k. LDS 16KB.
// (R21 ran this but its time was masked by the k_ic2 regression — the WC
// fold turned a 28us-floor compute problem into a 170us-floor gather:
// 16KB/sample random reads, 1.07GB total, VALUBusy 5%. Bytes before FLOPs.)
// ---------------------------------------------------------------------------
__global__ __attribute__((amdgpu_waves_per_eu(2, 8))) __launch_bounds__(256)
void k_siren(AllP P, const float* __restrict__ w2t)
{
    __shared__ float sbuf[MID * 8];     // 16 KB: h1 [k][m] during loop; h2 after

    const int tid = threadIdx.x;
    const int net = blockIdx.y;
    const int m0  = blockIdx.x * 8;
    NetP np;
    if (net == 0)      np = P.n[0];
    else if (net == 1) np = P.n[1];
    else               np = P.n[2];
    const float* wslab = w2t + (size_t)net * MID * MID;

    const int c  = tid & 63;
    const int w  = tid >> 6;          // wave 0..3 -> col quarter
    const int cw = w * 128 + c * 2;   // first of this thread's 2 cols

    // ---- fill h1[k][m] = sin(sin(4*(x_m*w1[k]+b1[k]))), 16 entries/thread
    {
        const float invG = 1.0f / (float)G;
        #pragma unroll 4
        for (int j = 0; j < 16; ++j) {
            const int idx = tid + j * 256;        // = k*8 + m
            const int k = idx >> 3, m = idx & 7;
            const float xv = ((float)(m0 + m) - 1.0f) * invG;
            const float z = 4.f * fmaf(xv, np.w1[k], np.b1[k]);
            sbuf[idx] = sinf(sinf(z));
        }
    }
    __syncthreads();

#define ACC_DECL(i) float2 a##i = make_float2(0.f, 0.f);
    ACC_DECL(0) ACC_DECL(1) ACC_DECL(2) ACC_DECL(3)
    ACC_DECL(4) ACC_DECL(5) ACC_DECL(6) ACC_DECL(7)

#define FMA2(i, hv) \
        a##i.x = fmaf(hv, wa.x, a##i.x); a##i.y = fmaf(hv, wa.y, a##i.y);

    // ---- K loop: barrier-free. 1 global b64 (W) + 2 broadcast LDS b128 (h).
    {
        const float* wp = wslab + cw;
        #pragma unroll 4
        for (int k = 0; k < MID; ++k) {
            const float2 wa = *reinterpret_cast<const float2*>(wp + (size_t)k * MID);
            const float4 hA = *reinterpret_cast<const float4*>(&sbuf[k * 8 + 0]);
            const float4 hB = *reinterpret_cast<const float4*>(&sbuf[k * 8 + 4]);
            FMA2(0, hA.x) FMA2(1, hA.y) FMA2(2, hA.z) FMA2(3, hA.w)
            FMA2(4, hB.x) FMA2(5, hB.y) FMA2(6, hB.z) FMA2(7, hB.w)
        }
    }
    __syncthreads();   // h1 no longer needed; sbuf becomes the h2 buffer

    {   // epilogue: h2 = sin(sin(4*(z + b2))) — this thread's 2 cols, 8 pts
        const float2 bv = *reinterpret_cast<const float2*>(np.b2 + cw);
#define SS1(v, b) v = sinf(sinf(4.f * ((v) + (b))));
#define SSROW(i) SS1(a##i.x, bv.x) SS1(a##i.y, bv.y)
        SSROW(0) SSROW(1) SSROW(2) SSROW(3)
        SSROW(4) SSROW(5) SSROW(6) SSROW(7)
    }

    // layer 3 stores: row i gets this thread's f2 at phys f2 (n2 ^ 2i);
    // since 2qq^2m = 2(qq^m) the f4 READ uses the proven key (qq^m).
    {
        const int n2 = w * 64 + c;   // logical float2 col index 0..255
#define L3ST(i) \
        *reinterpret_cast<float2*>(&sbuf[(i) * 512 + ((n2 ^ (2 * (i))) & 255) * 2]) = a##i;
        L3ST(0) L3ST(1) L3ST(2) L3ST(3)
        L3ST(4) L3ST(5) L3ST(6) L3ST(7)
    }
    __syncthreads();

    {   // m = tid&7 (point), jg = tid>>3 (0..31) -> output col jg
        const int m  = tid & 7;
        const int jg = tid >> 3;
        const float* wr = np.w3 + (size_t)jg * MID;
        float pa = 0.f, pb = 0.f;
        #pragma unroll 8
        for (int qq = 0; qq < 128; ++qq) {
            const float4 h  = *reinterpret_cast<const float4*>(
                &sbuf[m * 512 + ((qq ^ m) & 127) * 4]);
            const float4 wv = *reinterpret_cast<const float4*>(wr + qq * 4);
            pa = fmaf(h.y, wv.y, fmaf(h.x, wv.x, pa));
            pb = fmaf(h.w, wv.w, fmaf(h.z, wv.z, pb));
        }
        P.table[((size_t)net * PTS + (m0 + m)) * 32 + jg] = pa + pb + np.b3[jg];
    }
}

// ---------------------------------------------------------------------------
// Kernel 2: Catmull-Rom interp + Tucker contraction — ROUND-6 VERSION VERBATIM
// (measured ~93us; core staged in LDS once per block, consumed as wave-uniform
// broadcasts. Failed "improvements": R7/R10 2-sample (spill), R12 s_load
// (~145us), R21 WC-fold (206us memory-bound gather). DO NOT TOUCH.)
// ---------------------------------------------------------------------------
#define F4MA(acc, s, rp, k) { const float4 _v = (rp)[k]; \
    acc.x = fmaf((s), _v.x, acc.x); acc.y = fmaf((s), _v.y, acc.y); \
    acc.z = fmaf((s), _v.z, acc.z); acc.w = fmaf((s), _v.w, acc.w); }

#define GROW8(Pfx, w, rp, off) \
    F4MA(Pfx##0,(w),rp,(off)+0) F4MA(Pfx##1,(w),rp,(off)+1) \
    F4MA(Pfx##2,(w),rp,(off)+2) F4MA(Pfx##3,(w),rp,(off)+3) \
    F4MA(Pfx##4,(w),rp,(off)+4) F4MA(Pfx##5,(w),rp,(off)+5) \
    F4MA(Pfx##6,(w),rp,(off)+6) F4MA(Pfx##7,(w),rp,(off)+7)

// Catmull-Rom setup: x*G is EXACT in fp32 (power-of-two scale).
#define CRSETUP(x_, iv, c0, c1, c2, c3) \
    int iv; float c0, c1, c2, c3; { \
        float xx = (x_) * (float)G; \
        int i = (int)xx; i = i < 0 ? 0 : (i > G - 1 ? G - 1 : i); iv = i; \
        float t = xx - (float)i; \
        float t2 = t * t, t3 = t2 * t; \
        c0 = fmaf(-0.5f, t3, t2) - 0.5f * t; \
        c1 = fmaf(1.5f, t3, fmaf(-2.5f, t2, 1.f)); \
        c2 = fmaf(-1.5f, t3, fmaf(2.f, t2, 0.5f * t)); \
        c3 = 0.5f * (t3 - t2); }

__global__ __attribute__((amdgpu_waves_per_eu(2, 4))) __launch_bounds__(256)
void k_ic(const float* __restrict__ table, const float* __restrict__ core,
          const float* __restrict__ x, float* __restrict__ out)
{
    __shared__ float cs[8 * 1024];   // 32 KB: 8 r-rows of C per round
    __shared__ float red[256];

    const int tid = threadIdx.x;
    const int ls  = tid & 63;        // local sample
    const int rh  = tid >> 6;        // 0..3, wave-uniform; r = rb*8+rh*2+{0,1}
    const int g   = blockIdx.x * 64 + ls;

    const float xu = x[(size_t)g * 3 + 0];
    const float xv = x[(size_t)g * 3 + 1];
    const float xw = x[(size_t)g * 3 + 2];

#define DECLZ(Pn) float4 Pn = make_float4(0.f,0.f,0.f,0.f);
    DECLZ(W0) DECLZ(W1) DECLZ(W2) DECLZ(W3) DECLZ(W4) DECLZ(W5) DECLZ(W6) DECLZ(W7)
    DECLZ(V0) DECLZ(V1) DECLZ(V2) DECLZ(V3) DECLZ(V4) DECLZ(V5) DECLZ(V6) DECLZ(V7)
    float2 U0, U1, U2, U3;

    {   // W net (index 2)
        CRSETUP(xw, iw, c0, c1, c2, c3)
        const float4* rp = reinterpret_cast<const float4*>(
            table + ((size_t)2 * PTS + iw) * 32);
        GROW8(W, c0, rp, 0) GROW8(W, c1, rp, 8) GROW8(W, c2, rp, 16) GROW8(W, c3, rp, 24)
    }
    {   // V net (index 1)
        CRSETUP(xv, iv2, c0, c1, c2, c3)
        const float4* rp = reinterpret_cast<const float4*>(
            table + ((size_t)PTS + iv2) * 32);
        GROW8(V, c0, rp, 0) GROW8(V, c1, rp, 8) GROW8(V, c2, rp, 16) GROW8(V, c3, rp, 24)
    }
    {   // U net (index 0): this thread's 8 r-cols = rb*8 + rh*2 + {0,1}
        CRSETUP(xu, iu, c0, c1, c2, c3)
        const float2* up = reinterpret_cast<const float2*>(table + (size_t)iu * 32);
#define UROW(rbv, dst) { \
        const float2 t0 = up[0 * 16 + (rbv) * 4 + rh]; \
        const float2 t1 = up[1 * 16 + (rbv) * 4 + rh]; \
        const float2 t2 = up[2 * 16 + (rbv) * 4 + rh]; \
        const float2 t3 = up[3 * 16 + (rbv) * 4 + rh]; \
        dst.x = fmaf(c0,t0.x,fmaf(c1,t1.x,fmaf(c2,t2.x,c3*t3.x))); \
        dst.y = fmaf(c0,t0.y,fmaf(c1,t1.y,fmaf(c2,t2.y,c3*t3.y))); }
        UROW(0, U0) UROW(1, U1) UROW(2, U2) UROW(3, U3)
    }

#define TQC(rl, s, tq, Wv) { \
    const float4 c4 = *reinterpret_cast<const float4*>( \
        &cs[(rh * 2 + (rl)) * 1024 + (s) * 32 + (tq) * 4]); \
    aa = fmaf(Wv.w, c4.w, fmaf(Wv.z, c4.z, fmaf(Wv.y, c4.y, fmaf(Wv.x, c4.x, aa)))); }

#define SONE(rl, s, vcomp) { float aa = 0.f; \
    TQC(rl, s, 0, W0) TQC(rl, s, 1, W1) TQC(rl, s, 2, W2) TQC(rl, s, 3, W3) \
    TQC(rl, s, 4, W4) TQC(rl, s, 5, W5) TQC(rl, s, 6, W6) TQC(rl, s, 7, W7) \
    tracc = fmaf(vcomp, aa, tracc); }

#define SG(rl, sb, Vv) \
    SONE(rl, 4*(sb)+0, Vv.x) SONE(rl, 4*(sb)+1, Vv.y) \
    SONE(rl, 4*(sb)+2, Vv.z) SONE(rl, 4*(sb)+3, Vv.w)

#define RL1(rl, ucomp) { float tracc = 0.f; \
    SG(rl, 0, V0) SG(rl, 1, V1) SG(rl, 2, V2) SG(rl, 3, V3) \
    SG(rl, 4, V4) SG(rl, 5, V5) SG(rl, 6, V6) SG(rl, 7, V7) \
    o = fmaf(ucomp, tracc, o); }

#define RBLOCK(rb) { \
    __syncthreads(); \
    _Pragma("unroll") \
    for (int cc = 0; cc < 8; ++cc) \
        *reinterpret_cast<float4*>(&cs[cc * 1024 + tid * 4]) = \
            *reinterpret_cast<const float4*>(core + (size_t)((rb) * 8 + cc) * 1024 + tid * 4); \
    __syncthreads(); \
    RL1(0, U##rb.x) RL1(1, U##rb.y) }

    float o = 0.f;
    RBLOCK(0) RBLOCK(1) RBLOCK(2) RBLOCK(3)

    red[tid] = o;
    __syncthreads();
    if (tid < 64)
        out[blockIdx.x * 64 + tid] =
            red[tid] + red[tid + 64] + red[tid + 128] + red[tid + 192];
}

// ---------------------------------------------------------------------------
extern "C" void kernel_launch(void* const* d_in, const int* in_sizes, int n_in,
                              void* d_out, int out_size, void* d_ws, size_t ws_size,
                              hipStream_t stream)
{
    AllP P;
    for (int net = 0; net < 3; ++net) {
        const int b = 1 + net * 6;
        P.n[net].w1 = (const float*)d_in[b + 0];
        P.n[net].b1 = (const float*)d_in[b + 1];
        P.n[net].w2 = (const float*)d_in[b + 2];
        P.n[net].b2 = (const float*)d_in[b + 3];
        P.n[net].w3 = (const float*)d_in[b + 4];
        P.n[net].b3 = (const float*)d_in[b + 5];
    }
    const float* xin  = (const float*)d_in[0];
    const float* core = (const float*)d_in[19];
    float* wsf   = (float*)d_ws;
    float* table = wsf;                            // 3*4128*32 = 1.58 MB
    float* w2t   = wsf + (size_t)3 * PTS * 32;     // 3*512*512 = 3.00 MB
    P.table = table;

    k_prep <<<dim3(16, 16, 3), 256, 0, stream>>>(P, w2t);
    k_siren<<<dim3(NBLK, 3), 256, 0, stream>>>(P, w2t);
    k_ic   <<<NB / 64, 256, 0, stream>>>(table, core, xin, (float*)d_out);
}